// Round 10
// baseline (246.432 us; speedup 1.0000x reference)
//
#include <hip/hip_runtime.h>
#include <math.h>

// EdgeDetection: fused gray -> gauss3x3(sigma=0.8) -> scharr -> L2 mag, reflect-101
// Composite separable 5-tap: sx = (vert [3,10,3]*g) x (horiz [-1,0,1]*g), sy = transpose.
// R10: BARRIER-FREE STREAMING. Matrix of R2/R5/R6/R9 vs fillBuffer (6.8 TB/s) says:
// every barrier/phase structure convoys at ~2.9 TB/s; the chip wants max-TLP
// unstructured streams. Wave owns 256px x 2 rows; all 18 RGB f4 loads issued as one
// independent burst (R5's chained-ring flaw removed); gray+5-tap in regs; horizontal
// halo via shfl, wave-edge lanes load 1 reflected halo f4/row/ch (slot-select at true
// image edge). No LDS, no syncthreads. 4096 blocks (~4 generations), XCD-chunked
// strip swizzle so the 3x vertical row re-reads stay L2-hot.
// R11/R12: identical resubmits (R10 never ran - infra failures; OOB/hang audit clean).

#define IMG_H 1024
#define IMG_W 1024

// 1D gaussian sigma=0.8 k=3: e=exp(-0.78125); W0=1/(1+2e), W1=e/(1+2e)
#define W0 0.52201125f
#define W1 0.23899437f
// composite smooth taps conv([3,10,3],[W1,W0,W1]):
#define AV0 0.71698311f   // 3*W1
#define AV1 3.95597745f   // 3*W0 + 10*W1
#define AV2 6.65407872f   // 10*W0 + 6*W1

typedef float vf4 __attribute__((ext_vector_type(4)));

__device__ __forceinline__ int reflect101(int v, int n) {
    v = (v < 0) ? -v : v;
    return (v >= n) ? (2 * n - 2 - v) : v;
}

__device__ __forceinline__ float grayf(float r, float g, float b) {
    return 0.299f * r + 0.587f * g + 0.114f * b;
}

__global__ __launch_bounds__(256, 4)
void edge_kernel(const float* __restrict__ in, float* __restrict__ out) {
    const int lane = threadIdx.x & 63;
    const int wv   = threadIdx.x >> 6;          // 4 waves, 256px column band each
    const int bx   = blockIdx.x;                // 512 row-strips
    const int strip = (bx & 7) * 64 + (bx >> 3); // XCD-chunked: 64 consecutive strips/XCD
    const int b    = blockIdx.y;
    const int y0   = strip * 2;                 // 2 output rows per strip
    const int x4   = wv * 256 + lane * 4;

    const size_t plane = (size_t)IMG_H * IMG_W;
    const float* pr = in + (size_t)b * 3 * plane;
    const float* pg = pr + plane;
    const float* pb = pg + plane;
    float* po = out + (size_t)b * 3 * plane;

    const bool eL = (lane == 0), eR = (lane == 63);
    const bool eAny = eL || eR;
    const bool trueL = eL && (x4 == 0);
    const bool trueR = eR && (x4 == IMG_W - 4);
    // halo f4 base: left lanes read [x4-4..x4-1] (clamped), right read [x4+4..x4+7] (clamped)
    const int hx = eR ? (x4 + 4 > IMG_W - 4 ? IMG_W - 4 : x4 + 4)
                      : (x4 - 4 < 0 ? 0 : x4 - 4);

    // ---- one independent burst: 18 f4 loads (6 rows x RGB), + halo for 2/64 lanes ----
    float4 cR[6], cG[6], cB[6];
    float4 hR[6], hG[6], hB[6];
    int yy[6];
    #pragma unroll
    for (int r = 0; r < 6; ++r) {
        yy[r] = reflect101(y0 - 2 + r, IMG_H);
        const size_t o = (size_t)yy[r] * IMG_W + x4;
        cR[r] = *(const float4*)(pr + o);
        cG[r] = *(const float4*)(pg + o);
        cB[r] = *(const float4*)(pb + o);
    }
    if (eAny) {
        #pragma unroll
        for (int r = 0; r < 6; ++r) {
            const size_t o = (size_t)yy[r] * IMG_W + hx;
            hR[r] = *(const float4*)(pr + o);
            hG[r] = *(const float4*)(pg + o);
            hB[r] = *(const float4*)(pb + o);
        }
    }

    // ---- per row: gray, halo via shfl (+edge fixups), composite 5-tap h-pass ----
    float hs[6][4], hd[6][4];
    #pragma unroll
    for (int r = 0; r < 6; ++r) {
        float g0 = grayf(cR[r].x, cG[r].x, cB[r].x);
        float g1 = grayf(cR[r].y, cG[r].y, cB[r].y);
        float g2 = grayf(cR[r].z, cG[r].z, cB[r].z);
        float g3 = grayf(cR[r].w, cG[r].w, cB[r].w);
        float lm2 = __shfl_up(g2, 1);    // left neighbor's g2 = px x4-2
        float lm1 = __shfl_up(g3, 1);    // px x4-1
        float rp4 = __shfl_down(g0, 1);  // right neighbor's g0 = px x4+4
        float rp5 = __shfl_down(g1, 1);  // px x4+5
        if (eAny) {
            float h0 = grayf(hR[r].x, hG[r].x, hB[r].x);
            float h1 = grayf(hR[r].y, hG[r].y, hB[r].y);
            float h2 = grayf(hR[r].z, hG[r].z, hB[r].z);
            float h3 = grayf(hR[r].w, hG[r].w, hB[r].w);
            if (eL) {
                lm2 = h2;                 // interior: px x4-2; true edge: reflect(-2)=px2
                lm1 = trueL ? h1 : h3;    // true edge: reflect(-1)=px1
            } else {
                rp4 = trueR ? h2 : h0;    // true edge: reflect(1024)=px1022
                rp5 = h1;                 // interior px x4+5; true edge reflect(1025)=px1021
            }
        }
        hs[r][0] = AV0 * (lm2 + g2) + AV1 * (lm1 + g1) + AV2 * g0;
        hs[r][1] = AV0 * (lm1 + g3) + AV1 * (g0 + g2) + AV2 * g1;
        hs[r][2] = AV0 * (g0 + rp4) + AV1 * (g1 + g3) + AV2 * g2;
        hs[r][3] = AV0 * (g1 + rp5) + AV1 * (g2 + rp4) + AV2 * g3;
        hd[r][0] = W1 * (g2 - lm2) + W0 * (g1 - lm1);
        hd[r][1] = W1 * (g3 - lm1) + W0 * (g2 - g0);
        hd[r][2] = W1 * (rp4 - g0) + W0 * (g3 - g1);
        hd[r][3] = W1 * (rp5 - g1) + W0 * (rp4 - g2);
    }

    // ---- vertical pass + magnitude for 2 output rows ----
    #pragma unroll
    for (int t = 0; t < 2; ++t) {
        vf4 mag;
        #pragma unroll
        for (int k = 0; k < 4; ++k) {
            float sx = AV0 * (hd[t][k] + hd[t+4][k]) + AV1 * (hd[t+1][k] + hd[t+3][k]) + AV2 * hd[t+2][k];
            float sy = W1 * (hs[t+4][k] - hs[t][k]) + W0 * (hs[t+3][k] - hs[t+1][k]);
            mag[k] = sqrtf(sx * sx + sy * sy);
        }
        const size_t o = (size_t)(y0 + t) * IMG_W + x4;
        __builtin_nontemporal_store(mag, (vf4*)(po + o));
        __builtin_nontemporal_store(mag, (vf4*)(po + o + plane));
        __builtin_nontemporal_store(mag, (vf4*)(po + o + 2 * plane));
    }
}

extern "C" void kernel_launch(void* const* d_in, const int* in_sizes, int n_in,
                              void* d_out, int out_size, void* d_ws, size_t ws_size,
                              hipStream_t stream) {
    const float* in = (const float*)d_in[0];
    float* out = (float*)d_out;
    const int B = in_sizes[0] / (3 * IMG_H * IMG_W);
    dim3 grid(IMG_H / 2, B);   // 512 x 8 = 4096 blocks, no barriers anywhere
    edge_kernel<<<grid, dim3(256), 0, stream>>>(in, out);
}